// Round 1
// baseline (330.765 us; speedup 1.0000x reference)
//
#include <hip/hip_runtime.h>
#include <stdint.h>

#define V      768
#define FINC   32
#define FOUTC  32
#define XYZ    512
#define NB     2
#define ROWP   40      // padded LDS row stride in ushorts (80 B, 16B-aligned, conflict-benign)
#define MAXDEG 32
#define KCHEB  5

typedef unsigned short u16;
typedef unsigned int   u32;
typedef short bf16x8 __attribute__((ext_vector_type(8)));
typedef float f32x4  __attribute__((ext_vector_type(4)));

__device__ __forceinline__ u16 f2bf(float f) {
  u32 u = __float_as_uint(f);
  u32 r = u + 0x7fffu + ((u >> 16) & 1u);   // RNE
  return (u16)(r >> 16);
}
__device__ __forceinline__ float bflo(u32 w) { return __uint_as_float(w << 16); }
__device__ __forceinline__ float bfhi(u32 w) { return __uint_as_float(w & 0xffff0000u); }

// ---------- kernel 1: x [B,Fin,V,XYZ] f32 -> xT [B,XYZ,V,Fin] bf16 ----------
__global__ __launch_bounds__(512) void transpose_x(const float* __restrict__ x,
                                                   u16* __restrict__ xT) {
  int g = blockIdx.x;            // b*V + v
  int b = g / V, v = g - b * V;
  int t = threadIdx.x;           // xyz
  float vals[FINC];
  const float* src = x + ((size_t)(b * FINC) * V + v) * XYZ + t;
#pragma unroll
  for (int f = 0; f < FINC; ++f) vals[f] = src[(size_t)f * V * XYZ];   // coalesced over t
  u32 pw[16];
#pragma unroll
  for (int p = 0; p < 16; ++p)
    pw[p] = (u32)f2bf(vals[2 * p]) | ((u32)f2bf(vals[2 * p + 1]) << 16);
  uint4* dst = (uint4*)(xT + ((size_t)(b * XYZ + t) * V + v) * FINC);  // 64B per thread
#pragma unroll
  for (int q = 0; q < 4; ++q)
    dst[q] = make_uint4(pw[4 * q], pw[4 * q + 1], pw[4 * q + 2], pw[4 * q + 3]);
}

// ---------- kernel 2: deterministic ELL build (one wave per row) ----------
__global__ __launch_bounds__(64) void build_ell(const int* __restrict__ rows,
                                                const int* __restrict__ cols,
                                                const float* __restrict__ vals,
                                                int nnz,
                                                int* __restrict__ ecol,
                                                float* __restrict__ eval_,
                                                int* __restrict__ deg) {
  int v = blockIdx.x;
  int lane = threadIdx.x;
  int cnt = 0;
  for (int base = 0; base < nnz; base += 64) {
    int i = base + lane;
    bool m = (i < nnz) && (rows[i] == v);
    unsigned long long mask = __ballot(m);
    if (m) {
      int pos = cnt + __popcll(mask & ((1ull << lane) - 1ull));
      if (pos < MAXDEG) { ecol[v * MAXDEG + pos] = cols[i]; eval_[v * MAXDEG + pos] = vals[i]; }
    }
    cnt += __popcll(mask);
  }
  if (lane == 0) deg[v] = cnt < MAXDEG ? cnt : MAXDEG;
}

// ---------- kernel 3: fused recursion + MFMA GEMM ----------
__global__ __launch_bounds__(768) void cheb_main(
    const u16* __restrict__ xT, const int* __restrict__ ecol,
    const float* __restrict__ eval_, const int* __restrict__ deg,
    const float* __restrict__ weight, const float* __restrict__ bias,
    float* __restrict__ out) {
  __shared__ __align__(16) u16 Xb[V * ROWP];
  __shared__ __align__(16) u16 Yb[V * ROWP];

  int g = blockIdx.x;
  // XCD swizzle: XCD x handles xyz in [x*64, x*64+64) for both b -> L2 write-merge
  int xcd = g & 7, slot = g >> 3;
  int xyz = xcd * 64 + (slot & 63);
  int b = slot >> 6;
  int tid = threadIdx.x;
  int lane = tid & 63;
  int w = tid >> 6;               // wave 0..11
  int l15 = lane & 15, l4 = lane >> 4;

  // ---- load slice (contiguous 48 KB) into Xb (padded rows)
  {
    const uint4* src = (const uint4*)(xT + (size_t)(b * XYZ + xyz) * V * FINC);
    uint4* xb = (uint4*)Xb;
    int v = tid;
#pragma unroll
    for (int j = 0; j < 4; ++j) xb[v * 5 + j] = src[v * 4 + j];
  }
  __syncthreads();

  f32x4 acc[4][2];
#pragma unroll
  for (int a = 0; a < 4; ++a)
#pragma unroll
    for (int n = 0; n < 2; ++n) acc[a][n] = (f32x4){0.f, 0.f, 0.f, 0.f};

  // out[v,fout] += sum_fin Zb[v,fin] * W[k,fin,fout]   (A rows = v, B cols = fout)
  auto gemm_acc = [&](const u16* Zb, int k) {
    bf16x8 bfr[2];
#pragma unroll
    for (int n = 0; n < 2; ++n) {
#pragma unroll
      for (int j = 0; j < 8; ++j) {
        float wv = weight[(size_t)(k * FINC + l4 * 8 + j) * FOUTC + n * 16 + l15];
        bfr[n][j] = (short)f2bf(wv);
      }
    }
#pragma unroll
    for (int a = 0; a < 4; ++a) {
      int row = (w * 4 + a) * 16 + l15;
      bf16x8 af = *(const bf16x8*)(Zb + row * ROWP + l4 * 8);
#pragma unroll
      for (int n = 0; n < 2; ++n)
        acc[a][n] = __builtin_amdgcn_mfma_f32_16x16x32_bf16(af, bfr[n], acc[a][n], 0, 0, 0);
    }
  };

  // D[v,:] = (sub ? 2*L*S - D : L*S)[v,:]   — thread v owns row v; in-place-safe
  auto spmm = [&](const u16* S, u16* D, bool sub) {
    int v = tid;
    int dg = deg[v];
    float fa[FINC];
#pragma unroll
    for (int f = 0; f < FINC; ++f) fa[f] = 0.f;
    for (int e = 0; e < dg; ++e) {
      int   c  = ecol[v * MAXDEG + e];
      float fv = eval_[v * MAXDEG + e];
      const uint4* sp = (const uint4*)(S + c * ROWP);
#pragma unroll
      for (int j = 0; j < 4; ++j) {
        uint4 q = sp[j];
        u32 wq[4] = {q.x, q.y, q.z, q.w};
#pragma unroll
        for (int p = 0; p < 4; ++p) {
          fa[j * 8 + 2 * p]     += fv * bflo(wq[p]);
          fa[j * 8 + 2 * p + 1] += fv * bfhi(wq[p]);
        }
      }
    }
    uint4* dp = (uint4*)(D + v * ROWP);
#pragma unroll
    for (int j = 0; j < 4; ++j) {
      u32 o[4];
      if (sub) {
        uint4 q = dp[j];
        u32 wq[4] = {q.x, q.y, q.z, q.w};
#pragma unroll
        for (int p = 0; p < 4; ++p) {
          float r0 = 2.f * fa[j * 8 + 2 * p]     - bflo(wq[p]);
          float r1 = 2.f * fa[j * 8 + 2 * p + 1] - bfhi(wq[p]);
          o[p] = (u32)f2bf(r0) | ((u32)f2bf(r1) << 16);
        }
      } else {
#pragma unroll
        for (int p = 0; p < 4; ++p)
          o[p] = (u32)f2bf(fa[j * 8 + 2 * p]) | ((u32)f2bf(fa[j * 8 + 2 * p + 1]) << 16);
      }
      dp[j] = make_uint4(o[0], o[1], o[2], o[3]);
    }
  };

  // Phase schedule: GEMM reads the buffer spmm does NOT write in the same phase.
  gemm_acc(Xb, 0);            // T0 = x0
  spmm(Xb, Yb, false);        // T1 = L*T0
  __syncthreads();
  gemm_acc(Yb, 1);
  spmm(Yb, Xb, true);         // T2 = 2*L*T1 - T0 (in place over T0)
  __syncthreads();
  gemm_acc(Xb, 2);
  spmm(Xb, Yb, true);         // T3
  __syncthreads();
  gemm_acc(Yb, 3);
  spmm(Yb, Xb, true);         // T4
  __syncthreads();
  gemm_acc(Xb, 4);

  // ---- epilogue: C frag mapping col=lane&15, row=(lane>>4)*4+r  [m89]
#pragma unroll
  for (int n = 0; n < 2; ++n) {
    float bsv = bias[n * 16 + l15];
    int fout = n * 16 + l15;
#pragma unroll
    for (int a = 0; a < 4; ++a) {
      int vrow0 = (w * 4 + a) * 16 + l4 * 4;
#pragma unroll
      for (int r = 0; r < 4; ++r) {
        out[((size_t)(b * FOUTC + fout) * V + (vrow0 + r)) * XYZ + xyz] = acc[a][n][r] + bsv;
      }
    }
  }
}

extern "C" void kernel_launch(void* const* d_in, const int* in_sizes, int n_in,
                              void* d_out, int out_size, void* d_ws, size_t ws_size,
                              hipStream_t stream) {
  const int*   lap_rows = (const int*)d_in[0];
  const int*   lap_cols = (const int*)d_in[1];
  const float* lap_vals = (const float*)d_in[2];
  const float* x        = (const float*)d_in[3];
  const float* weight   = (const float*)d_in[4];
  const float* bias     = (const float*)d_in[5];
  float* out = (float*)d_out;
  int nnz = in_sizes[0];

  char* ws = (char*)d_ws;
  const size_t XT_BYTES  = (size_t)NB * XYZ * V * FINC * sizeof(u16);  // 50,331,648
  u16*   xT    = (u16*)ws;
  int*   ecol  = (int*)(ws + XT_BYTES);
  float* eval_ = (float*)(ws + XT_BYTES + (size_t)V * MAXDEG * 4);
  int*   deg   = (int*)(ws + XT_BYTES + (size_t)V * MAXDEG * 8);

  hipLaunchKernelGGL(transpose_x, dim3(NB * V), dim3(512), 0, stream, x, xT);
  hipLaunchKernelGGL(build_ell, dim3(V), dim3(64), 0, stream,
                     lap_rows, lap_cols, lap_vals, nnz, ecol, eval_, deg);
  hipLaunchKernelGGL(cheb_main, dim3(NB * XYZ), dim3(768), 0, stream,
                     xT, ecol, eval_, deg, weight, bias, out);
}